// Round 9
// baseline (760.861 us; speedup 1.0000x reference)
//
#include <hip/hip_runtime.h>

#define NT 8192      // tokens = B*S
#define DIM 1024     // D
#define FDIM 4096    // F
#define NEXP 8       // experts

typedef __attribute__((ext_vector_type(8))) short bfx8;   // 8 bf16 (4 VGPRs)
typedef __attribute__((ext_vector_type(4))) float fx4;    // MFMA accumulator

__device__ __forceinline__ unsigned short f2bf(float f) {
  union { float f; unsigned u; } v; v.f = f;
  unsigned u = v.u;
  unsigned r = u + 0x7FFFu + ((u >> 16) & 1u);   // round-to-nearest-even
  return (unsigned short)(r >> 16);
}

__device__ __forceinline__ void gload16(const void* g, void* l) {
  __builtin_amdgcn_global_load_lds(
      (const __attribute__((address_space(1))) unsigned int*)g,
      (__attribute__((address_space(3))) unsigned int*)l, 16, 0, 0);
}

// ---------------- zero counters ----------------
__global__ void k_zero(int* __restrict__ counts) {
  if (threadIdx.x < NEXP) counts[threadIdx.x] = 0;
}

// ---------------- routing: argmax affinity + alpha + LN stats ----------------
__global__ __launch_bounds__(256) void k_routing(
    const float* __restrict__ x, const float* __restrict__ cent,
    int* __restrict__ eid, float* __restrict__ alpha, float2* __restrict__ stats,
    int* __restrict__ counts)
{
  const int t = blockIdx.x, tid = threadIdx.x;
  const float4 xv = ((const float4*)(x + (size_t)t * DIM))[tid];
  float acc[NEXP];
#pragma unroll
  for (int e = 0; e < NEXP; ++e) {
    const float4 cv = ((const float4*)(cent + (size_t)e * DIM))[tid];
    acc[e] = xv.x * cv.x + xv.y * cv.y + xv.z * cv.z + xv.w * cv.w;
  }
  float s = xv.x + xv.y + xv.z + xv.w;
  float ss = xv.x * xv.x + xv.y * xv.y + xv.z * xv.z + xv.w * xv.w;
#pragma unroll
  for (int off = 32; off > 0; off >>= 1) {
#pragma unroll
    for (int e = 0; e < NEXP; ++e) acc[e] += __shfl_down(acc[e], off);
    s += __shfl_down(s, off); ss += __shfl_down(ss, off);
  }
  __shared__ float part[4][NEXP];
  __shared__ float ps[4], pss[4];
  const int lane = tid & 63, w = tid >> 6;
  if (lane == 0) {
#pragma unroll
    for (int e = 0; e < NEXP; ++e) part[w][e] = acc[e];
    ps[w] = s; pss[w] = ss;
  }
  __syncthreads();
  if (tid == 0) {
    int best = 0; float bv = -1e30f;
#pragma unroll
    for (int e = 0; e < NEXP; ++e) {
      float v = part[0][e] + part[1][e] + part[2][e] + part[3][e];
      if (v > bv) { bv = v; best = e; }   // strict >: first max (matches argmax)
    }
    eid[t] = best;
    alpha[t] = 1.0f / (1.0f + expf(-bv));
    atomicAdd(&counts[best], 1);
    const float sum = ps[0] + ps[1] + ps[2] + ps[3];
    const float sq  = pss[0] + pss[1] + pss[2] + pss[3];
    const float mu = sum * (1.0f / DIM);
    const float var = sq * (1.0f / DIM) - mu * mu;
    stats[t] = make_float2(mu, rsqrtf(var + 1e-5f));
  }
}

// ---------------- exclusive scan of 8 counts ----------------
__global__ void k_scan(const int* __restrict__ counts, int* __restrict__ bs, int* __restrict__ cur) {
  if (threadIdx.x == 0) {
    int s = 0;
    for (int e = 0; e < NEXP; ++e) { bs[e] = s; cur[e] = s; s += counts[e]; }
  }
}

// ---------------- LayerNorm apply + counting-sort scatter (bf16) ----------------
__global__ __launch_bounds__(256) void k_ln_scatter(
    const float* __restrict__ x, const float* __restrict__ g, const float* __restrict__ b,
    const int* __restrict__ eid, const float2* __restrict__ stats, int* __restrict__ cur,
    int* __restrict__ row_tok, unsigned short* __restrict__ xln)
{
  const int t = blockIdx.x, tid = threadIdx.x;
  __shared__ int spos;
  const int e = eid[t];
  if (tid == 0) {
    const int pos = atomicAdd(&cur[e], 1);
    row_tok[pos] = t;
    spos = pos;
  }
  const float4 xv = ((const float4*)(x + (size_t)t * DIM))[tid];
  const float2 st = stats[t];
  const float mu = st.x, rstd = st.y;
  const float4 gv = ((const float4*)(g + (size_t)e * DIM))[tid];
  const float4 bv = ((const float4*)(b + (size_t)e * DIM))[tid];
  __syncthreads();
  const int pos = spos;
  ushort4 o;
  o.x = f2bf((xv.x - mu) * rstd * gv.x + bv.x);
  o.y = f2bf((xv.y - mu) * rstd * gv.y + bv.y);
  o.z = f2bf((xv.z - mu) * rstd * gv.z + bv.z);
  o.w = f2bf((xv.w - mu) * rstd * gv.w + bv.w);
  ((ushort4*)(xln + (size_t)pos * DIM))[tid] = o;
}

// ---------------- transpose fp32 [R][C] -> bf16 [C][R], 64x128 tiles ----------------
__global__ __launch_bounds__(256) void k_transpose(
    const float* __restrict__ in, unsigned short* __restrict__ outT, int R, int C)
{
  __shared__ float T[64 * 128];
  const int e = blockIdx.z;
  const float* src = in + (size_t)e * R * C;
  unsigned short* dst = outT + (size_t)e * R * C;
  const int r0 = blockIdx.y * 64, c0 = blockIdx.x * 128;
  const int t = threadIdx.x, lane = t & 63, wv = t >> 6;
  const int rsub = wv * 2 + (lane >> 5);           // 0..7, == row&7 for all i
  const int cb = (lane & 31) ^ rsub;               // swizzled source col-block
#pragma unroll
  for (int i = 0; i < 8; ++i) {
    const int rbase = i * 8 + wv * 2;              // wave-uniform row pair
    gload16(src + (size_t)(r0 + rbase + (lane >> 5)) * C + c0 + cb * 4,
            &T[rbase * 128]);
  }
  __syncthreads();
#pragma unroll
  for (int it = 0; it < 4; ++it) {
    const int c = (t >> 3) + it * 32, q = t & 7;
    unsigned short o[8];
#pragma unroll
    for (int u = 0; u < 8; ++u)
      o[u] = f2bf(T[(q * 8 + u) * 128 + ((((c >> 2) ^ u) << 2) | (c & 3))]);
    *(uint4*)(dst + (size_t)(c0 + c) * R + r0 + q * 8) = *(const uint4*)o;
  }
}

// ---------------- persistent grouped MFMA GEMM, 128xBN tile, BK=32, 4 waves ----------------
// Grid = NEXP * (N/BN) * P, ALL blocks active: block p handles m-tiles
// p, p+P, ... of its expert (exact balance for any counts). Inner loop is the
// R4-proven single-buffer 2-barrier structure. bid&7 = expert (== XCD);
// within expert, p fastest so concurrent blocks share one B panel in L2.
template<int K, int N, int BN, bool FIRST>
__global__ __launch_bounds__(256) void k_gemm(
    const unsigned short* __restrict__ A,
    const unsigned short* __restrict__ Bt,
    const float* __restrict__ bias,
    const int* __restrict__ bs, const int* __restrict__ counts,
    unsigned short* __restrict__ Hout,
    const int* __restrict__ row_tok, const float* __restrict__ alpha,
    const float* __restrict__ xin, float* __restrict__ out)
{
  constexpr int P = 8;              // m-stride in tiles
  constexpr int JB = BN / 32;       // per-wave n fragments
  constexpr int GBN = BN / 64;      // gload16 per B stage

  const int bid = blockIdx.x;
  const int e = bid & 7;
  const int idx = bid >> 3;
  const int p = idx % P;
  const int n0 = (idx / P) * BN;

  const int cnt = counts[e];
  const int rbase = bs[e];

  __shared__ unsigned short lA[128 * 32];   // linear (global_load_lds dest)
  __shared__ unsigned short lB[BN * 32];

  const int tid = threadIdx.x;
  const int lane = tid & 63, wv = tid >> 6;
  const int wm = (wv >> 1) * 64, wn = (wv & 1) * (BN / 2);
  const int lr = lane & 15, lg = lane >> 4;

  const unsigned short* Bte = Bt + (size_t)e * N * K;

  // fixed per-thread staging geometry
  const int arow[2] = { tid >> 2, (256 + tid) >> 2 };       // A rows for chunks 0/1
  const int akq = (tid & 3) * 8;
  const unsigned short* bP[GBN];
#pragma unroll
  for (int i = 0; i < GBN; ++i) {
    const int g = i * 256 + tid;
    bP[i] = Bte + (size_t)(n0 + (g >> 2)) * K + (g & 3) * 8;
  }
  const float* be = bias + (size_t)e * N;

  for (int m0 = p * 128; m0 < cnt; m0 += P * 128) {
    const unsigned short* aP[2];
#pragma unroll
    for (int q = 0; q < 2; ++q) {
      int ar = rbase + m0 + arow[q];
      ar = ar < NT ? ar : NT - 1;             // clamp: pad rows masked at epilogue
      aP[q] = A + (size_t)ar * K + akq;
    }

    fx4 acc[4][JB] = {};

    for (int k0 = 0; k0 < K; k0 += 32) {
      gload16(aP[0] + k0, &lA[(0 * 4 + wv) * 512]);
      gload16(aP[1] + k0, &lA[(1 * 4 + wv) * 512]);
#pragma unroll
      for (int i = 0; i < GBN; ++i)
        gload16(bP[i] + k0, &lB[(i * 4 + wv) * 512]);
      __syncthreads();                        // compiler-managed vmcnt drain
      bfx8 bf[JB];
#pragma unroll
      for (int j = 0; j < JB; ++j)
        bf[j] = *(const bfx8*)(&lB[(wn + j * 16 + lr) * 32 + lg * 8]);
#pragma unroll
      for (int i = 0; i < 4; ++i) {
        const bfx8 af = *(const bfx8*)(&lA[(wm + i * 16 + lr) * 32 + lg * 8]);
#pragma unroll
        for (int j = 0; j < JB; ++j)
          acc[i][j] = __builtin_amdgcn_mfma_f32_16x16x32_bf16(af, bf[j], acc[i][j], 0, 0, 0);
      }
      __syncthreads();
    }

    if constexpr (FIRST) {
#pragma unroll
      for (int i = 0; i < 4; ++i) {
#pragma unroll
        for (int r2 = 0; r2 < 4; ++r2) {
          const int rl = wm + i * 16 + lg * 4 + r2;
          if (m0 + rl >= cnt) continue;
          unsigned short* hrow = Hout + (size_t)(rbase + m0 + rl) * N;
#pragma unroll
          for (int j = 0; j < JB; ++j) {
            const int col = n0 + wn + j * 16 + lr;
            float v = acc[i][j][r2] + be[col];
            hrow[col] = f2bf(v > 0.f ? v : 0.f);
          }
        }
      }
    } else {
#pragma unroll
      for (int i = 0; i < 4; ++i) {
#pragma unroll
        for (int r2 = 0; r2 < 4; ++r2) {
          const int rl = wm + i * 16 + lg * 4 + r2;
          if (m0 + rl >= cnt) continue;
          const int tok = row_tok[rbase + m0 + rl];
          const float al = alpha[tok];
          const float* xrow = xin + (size_t)tok * N;
          float* orow = out + (size_t)tok * N;
#pragma unroll
          for (int j = 0; j < JB; ++j) {
            const int col = n0 + wn + j * 16 + lr;
            orow[col] = xrow[col] + al * (acc[i][j][r2] + be[col]);
          }
        }
      }
    }
  }
}

extern "C" void kernel_launch(void* const* d_in, const int* in_sizes, int n_in,
                              void* d_out, int out_size, void* d_ws, size_t ws_size,
                              hipStream_t stream)
{
  const float* x    = (const float*)d_in[0];
  const float* cent = (const float*)d_in[1];
  const float* ln_g = (const float*)d_in[2];
  const float* ln_b = (const float*)d_in[3];
  const float* w1   = (const float*)d_in[4];
  const float* b1   = (const float*)d_in[5];
  const float* w2   = (const float*)d_in[6];
  const float* b2   = (const float*)d_in[7];
  float* out = (float*)d_out;

  char* ws = (char*)d_ws;
  unsigned short* xln  = (unsigned short*)(ws);                          // 16 MB [NT][DIM] bf16
  unsigned short* hbuf = (unsigned short*)(ws + (16ull << 20));          // 64 MB [NT][FDIM] bf16
  unsigned short* w1t  = (unsigned short*)(ws + (80ull << 20));          // 64 MB [E][F][D] bf16
  unsigned short* w2t  = (unsigned short*)(ws + (144ull << 20));         // 64 MB [E][D][F] bf16
  char* tail = ws + (208ull << 20);
  int*    eid    = (int*)(tail);
  float*  alpha  = (float*)(tail + 32768);
  int*    rowtok = (int*)(tail + 65536);
  int*    counts = (int*)(tail + 98304);
  int*    basep  = counts + 16;
  int*    cur    = counts + 32;
  float2* stats  = (float2*)(tail + 131072);

  k_zero<<<1, 64, 0, stream>>>(counts);
  k_routing<<<NT, 256, 0, stream>>>(x, cent, eid, alpha, stats, counts);
  k_scan<<<1, 1, 0, stream>>>(counts, basep, cur);
  k_ln_scatter<<<NT, 256, 0, stream>>>(x, ln_g, ln_b, eid, stats, cur, rowtok, xln);
  k_transpose<<<dim3(FDIM / 128, DIM / 64, NEXP), 256, 0, stream>>>(w1, w1t, DIM, FDIM);
  k_transpose<<<dim3(DIM / 128, FDIM / 64, NEXP), 256, 0, stream>>>(w2, w2t, FDIM, DIM);
  k_gemm<DIM, FDIM, 128, true><<<NEXP * (FDIM / 128) * 8, 256, 0, stream>>>(
      xln, w1t, b1, basep, counts, hbuf, nullptr, nullptr, nullptr, nullptr);
  k_gemm<FDIM, DIM, 64, false><<<NEXP * (DIM / 64) * 8, 256, 0, stream>>>(
      hbuf, w2t, b2, basep, counts, nullptr, rowtok, alpha, x, out);
}

// Round 10
// 533.663 us; speedup vs baseline: 1.4257x; 1.4257x over previous
//
#include <hip/hip_runtime.h>

#define NT 8192      // tokens = B*S
#define DIM 1024     // D
#define FDIM 4096    // F
#define NEXP 8       // experts

typedef __attribute__((ext_vector_type(8))) short bfx8;   // 8 bf16 (4 VGPRs)
typedef __attribute__((ext_vector_type(4))) float fx4;    // MFMA accumulator

__device__ __forceinline__ unsigned short f2bf(float f) {
  union { float f; unsigned u; } v; v.f = f;
  unsigned u = v.u;
  unsigned r = u + 0x7FFFu + ((u >> 16) & 1u);   // round-to-nearest-even
  return (unsigned short)(r >> 16);
}

__device__ __forceinline__ void gload16(const void* g, void* l) {
  __builtin_amdgcn_global_load_lds(
      (const __attribute__((address_space(1))) unsigned int*)g,
      (__attribute__((address_space(3))) unsigned int*)l, 16, 0, 0);
}

// ---------------- zero counters ----------------
__global__ void k_zero(int* __restrict__ counts) {
  if (threadIdx.x < NEXP) counts[threadIdx.x] = 0;
}

// ---------------- routing: argmax affinity + alpha + LN stats ----------------
__global__ __launch_bounds__(256) void k_routing(
    const float* __restrict__ x, const float* __restrict__ cent,
    int* __restrict__ eid, float* __restrict__ alpha, float2* __restrict__ stats,
    int* __restrict__ counts)
{
  const int t = blockIdx.x, tid = threadIdx.x;
  const float4 xv = ((const float4*)(x + (size_t)t * DIM))[tid];
  float acc[NEXP];
#pragma unroll
  for (int e = 0; e < NEXP; ++e) {
    const float4 cv = ((const float4*)(cent + (size_t)e * DIM))[tid];
    acc[e] = xv.x * cv.x + xv.y * cv.y + xv.z * cv.z + xv.w * cv.w;
  }
  float s = xv.x + xv.y + xv.z + xv.w;
  float ss = xv.x * xv.x + xv.y * xv.y + xv.z * xv.z + xv.w * xv.w;
#pragma unroll
  for (int off = 32; off > 0; off >>= 1) {
#pragma unroll
    for (int e = 0; e < NEXP; ++e) acc[e] += __shfl_down(acc[e], off);
    s += __shfl_down(s, off); ss += __shfl_down(ss, off);
  }
  __shared__ float part[4][NEXP];
  __shared__ float ps[4], pss[4];
  const int lane = tid & 63, w = tid >> 6;
  if (lane == 0) {
#pragma unroll
    for (int e = 0; e < NEXP; ++e) part[w][e] = acc[e];
    ps[w] = s; pss[w] = ss;
  }
  __syncthreads();
  if (tid == 0) {
    int best = 0; float bv = -1e30f;
#pragma unroll
    for (int e = 0; e < NEXP; ++e) {
      float v = part[0][e] + part[1][e] + part[2][e] + part[3][e];
      if (v > bv) { bv = v; best = e; }   // strict >: first max (matches argmax)
    }
    eid[t] = best;
    alpha[t] = 1.0f / (1.0f + expf(-bv));
    atomicAdd(&counts[best], 1);
    const float sum = ps[0] + ps[1] + ps[2] + ps[3];
    const float sq  = pss[0] + pss[1] + pss[2] + pss[3];
    const float mu = sum * (1.0f / DIM);
    const float var = sq * (1.0f / DIM) - mu * mu;
    stats[t] = make_float2(mu, rsqrtf(var + 1e-5f));
  }
}

// ---------------- exclusive scan of 8 counts ----------------
__global__ void k_scan(const int* __restrict__ counts, int* __restrict__ bs, int* __restrict__ cur) {
  if (threadIdx.x == 0) {
    int s = 0;
    for (int e = 0; e < NEXP; ++e) { bs[e] = s; cur[e] = s; s += counts[e]; }
  }
}

// ---------------- LayerNorm apply + counting-sort scatter (bf16) ----------------
__global__ __launch_bounds__(256) void k_ln_scatter(
    const float* __restrict__ x, const float* __restrict__ g, const float* __restrict__ b,
    const int* __restrict__ eid, const float2* __restrict__ stats, int* __restrict__ cur,
    int* __restrict__ row_tok, unsigned short* __restrict__ xln)
{
  const int t = blockIdx.x, tid = threadIdx.x;
  __shared__ int spos;
  const int e = eid[t];
  if (tid == 0) {
    const int pos = atomicAdd(&cur[e], 1);
    row_tok[pos] = t;
    spos = pos;
  }
  const float4 xv = ((const float4*)(x + (size_t)t * DIM))[tid];
  const float2 st = stats[t];
  const float mu = st.x, rstd = st.y;
  const float4 gv = ((const float4*)(g + (size_t)e * DIM))[tid];
  const float4 bv = ((const float4*)(b + (size_t)e * DIM))[tid];
  __syncthreads();
  const int pos = spos;
  ushort4 o;
  o.x = f2bf((xv.x - mu) * rstd * gv.x + bv.x);
  o.y = f2bf((xv.y - mu) * rstd * gv.y + bv.y);
  o.z = f2bf((xv.z - mu) * rstd * gv.z + bv.z);
  o.w = f2bf((xv.w - mu) * rstd * gv.w + bv.w);
  ((ushort4*)(xln + (size_t)pos * DIM))[tid] = o;
}

// ---------------- transpose fp32 [R][C] -> bf16 [C][R], 64x128 tiles ----------------
__global__ __launch_bounds__(256) void k_transpose(
    const float* __restrict__ in, unsigned short* __restrict__ outT, int R, int C)
{
  __shared__ float T[64 * 128];
  const int e = blockIdx.z;
  const float* src = in + (size_t)e * R * C;
  unsigned short* dst = outT + (size_t)e * R * C;
  const int r0 = blockIdx.y * 64, c0 = blockIdx.x * 128;
  const int t = threadIdx.x, lane = t & 63, wv = t >> 6;
  const int rsub = wv * 2 + (lane >> 5);           // 0..7, == row&7 for all i
  const int cb = (lane & 31) ^ rsub;               // swizzled source col-block
#pragma unroll
  for (int i = 0; i < 8; ++i) {
    const int rbase = i * 8 + wv * 2;              // wave-uniform row pair
    gload16(src + (size_t)(r0 + rbase + (lane >> 5)) * C + c0 + cb * 4,
            &T[rbase * 128]);
  }
  __syncthreads();
#pragma unroll
  for (int it = 0; it < 4; ++it) {
    const int c = (t >> 3) + it * 32, q = t & 7;
    unsigned short o[8];
#pragma unroll
    for (int u = 0; u < 8; ++u)
      o[u] = f2bf(T[(q * 8 + u) * 128 + ((((c >> 2) ^ u) << 2) | (c & 3))]);
    *(uint4*)(dst + (size_t)(c0 + c) * R + r0 + q * 8) = *(const uint4*)o;
  }
}

// ---------------- grouped MFMA GEMM, 128x128 tile, BK=32, 4 waves ----------------
// R4-proven single-buffer 2-barrier K-loop + LDS-bounce epilogue:
// acc (+bias/relu) -> 32x132 fp32 LDS tile per i-quadrant -> coalesced
// dwordx4 stores (GEMM1: bf16x8; GEMM2: float4 gated residual).
// Grid 1D: expert = bid&7 (== XCD), n-panel, m fastest (weights L2-resident).
template<int K, int N, bool FIRST>
__global__ __launch_bounds__(256) void k_gemm(
    const unsigned short* __restrict__ A,
    const unsigned short* __restrict__ Bt,
    const float* __restrict__ bias,
    const int* __restrict__ bs, const int* __restrict__ counts,
    unsigned short* __restrict__ Hout,
    const int* __restrict__ row_tok, const float* __restrict__ alpha,
    const float* __restrict__ xin, float* __restrict__ out)
{
  const int MB = NT / 128;
  const int bid = blockIdx.x;
  const int e = bid & 7;
  const int l = bid >> 3;
  const int m0 = (l % MB) * 128;               // m fastest
  const int cnt = counts[e];
  if (m0 >= cnt) return;
  const int n0 = (l / MB) * 128;
  const int rbase = bs[e];

  // 16.9KB shared: K-loop uses [0,16KB) as lA/lB; epilogue reuses as 32x132 fp32
  __shared__ __align__(16) char smem[32 * 132 * 4];
  unsigned short* lA = (unsigned short*)smem;
  unsigned short* lB = (unsigned short*)(smem + 8192);
  float* Lf = (float*)smem;

  const int tid = threadIdx.x;
  const int lane = tid & 63, wv = tid >> 6;
  const int wm = (wv >> 1) * 64, wn = (wv & 1) * 64;
  const int lr = lane & 15, lg = lane >> 4;

  fx4 acc[4][4] = {};

  const unsigned short* Bte = Bt + (size_t)e * N * K;

  // staging: chunk g = p*256+tid -> row g>>2, k-off (g&3)*8;
  // LDS linear elem offset 8*g = wave-uniform (p*4+wv)*512 + lane*8.
  const unsigned short* aP[2];
  const unsigned short* bP[2];
#pragma unroll
  for (int p = 0; p < 2; ++p) {
    const int g = p * 256 + tid;
    const int row = g >> 2, kq = (g & 3) * 8;
    int ar = rbase + m0 + row;
    ar = ar < NT ? ar : NT - 1;               // clamp: pad rows masked at epilogue
    aP[p] = A + (size_t)ar * K + kq;
    bP[p] = Bte + (size_t)(n0 + row) * K + kq;
  }

  for (int k0 = 0; k0 < K; k0 += 32) {
    gload16(aP[0] + k0, &lA[(0 * 4 + wv) * 512]);
    gload16(aP[1] + k0, &lA[(1 * 4 + wv) * 512]);
    gload16(bP[0] + k0, &lB[(0 * 4 + wv) * 512]);
    gload16(bP[1] + k0, &lB[(1 * 4 + wv) * 512]);
    __syncthreads();                          // compiler-managed vmcnt drain
    bfx8 bf[4];
#pragma unroll
    for (int j = 0; j < 4; ++j)
      bf[j] = *(const bfx8*)(&lB[(wn + j * 16 + lr) * 32 + lg * 8]);
#pragma unroll
    for (int i = 0; i < 4; ++i) {
      const bfx8 af = *(const bfx8*)(&lA[(wm + i * 16 + lr) * 32 + lg * 8]);
#pragma unroll
      for (int j = 0; j < 4; ++j)
        acc[i][j] = __builtin_amdgcn_mfma_f32_16x16x32_bf16(af, bf[j], acc[i][j], 0, 0, 0);
    }
    __syncthreads();
  }

  // bias for this thread's 4 columns
  const float* be = bias + (size_t)e * N;
  float bcol[4];
#pragma unroll
  for (int j = 0; j < 4; ++j) bcol[j] = be[n0 + wn + j * 16 + lr];

#pragma unroll
  for (int i = 0; i < 4; ++i) {
    __syncthreads();                          // protect LDS reuse
#pragma unroll
    for (int r2 = 0; r2 < 4; ++r2) {
      const int rowp = (wv >> 1) * 16 + lg * 4 + r2;    // 0..31
#pragma unroll
      for (int j = 0; j < 4; ++j) {
        float v = acc[i][j][r2] + bcol[j];
        if (FIRST) v = v > 0.f ? v : 0.f;
        Lf[rowp * 132 + wn + j * 16 + lr] = v;
      }
    }
    __syncthreads();
    if constexpr (FIRST) {
#pragma unroll
      for (int s = 0; s < 2; ++s) {
        const int tsk = tid + 256 * s;                  // 0..511
        const int rr = tsk >> 4, cg = tsk & 15;
        const int ra = i * 16 + ((rr >> 4) << 6) + (rr & 15);
        if (m0 + ra < cnt) {
          const float4 a = *(const float4*)&Lf[rr * 132 + cg * 8];
          const float4 b = *(const float4*)&Lf[rr * 132 + cg * 8 + 4];
          unsigned short o[8] = { f2bf(a.x), f2bf(a.y), f2bf(a.z), f2bf(a.w),
                                  f2bf(b.x), f2bf(b.y), f2bf(b.z), f2bf(b.w) };
          *(uint4*)(Hout + (size_t)(rbase + m0 + ra) * N + n0 + cg * 8) =
              *(const uint4*)o;
        }
      }
    } else {
#pragma unroll
      for (int s = 0; s < 4; ++s) {
        const int tsk = tid + 256 * s;                  // 0..1023
        const int rr = tsk >> 5, c4 = tsk & 31;
        const int ra = i * 16 + ((rr >> 4) << 6) + (rr & 15);
        if (m0 + ra < cnt) {
          const int tok = row_tok[rbase + m0 + ra];
          const float al = alpha[tok];
          const float4 v = *(const float4*)&Lf[rr * 132 + c4 * 4];
          const float4 xr = *(const float4*)(xin + (size_t)tok * N + n0 + c4 * 4);
          float4 o;
          o.x = xr.x + al * v.x;
          o.y = xr.y + al * v.y;
          o.z = xr.z + al * v.z;
          o.w = xr.w + al * v.w;
          *(float4*)(out + (size_t)tok * N + n0 + c4 * 4) = o;
        }
      }
    }
  }
}

extern "C" void kernel_launch(void* const* d_in, const int* in_sizes, int n_in,
                              void* d_out, int out_size, void* d_ws, size_t ws_size,
                              hipStream_t stream)
{
  const float* x    = (const float*)d_in[0];
  const float* cent = (const float*)d_in[1];
  const float* ln_g = (const float*)d_in[2];
  const float* ln_b = (const float*)d_in[3];
  const float* w1   = (const float*)d_in[4];
  const float* b1   = (const float*)d_in[5];
  const float* w2   = (const float*)d_in[6];
  const float* b2   = (const float*)d_in[7];
  float* out = (float*)d_out;

  char* ws = (char*)d_ws;
  unsigned short* xln  = (unsigned short*)(ws);                          // 16 MB [NT][DIM] bf16
  unsigned short* hbuf = (unsigned short*)(ws + (16ull << 20));          // 64 MB [NT][FDIM] bf16
  unsigned short* w1t  = (unsigned short*)(ws + (80ull << 20));          // 64 MB [E][F][D] bf16
  unsigned short* w2t  = (unsigned short*)(ws + (144ull << 20));         // 64 MB [E][D][F] bf16
  char* tail = ws + (208ull << 20);
  int*    eid    = (int*)(tail);
  float*  alpha  = (float*)(tail + 32768);
  int*    rowtok = (int*)(tail + 65536);
  int*    counts = (int*)(tail + 98304);
  int*    basep  = counts + 16;
  int*    cur    = counts + 32;
  float2* stats  = (float2*)(tail + 131072);

  k_zero<<<1, 64, 0, stream>>>(counts);
  k_routing<<<NT, 256, 0, stream>>>(x, cent, eid, alpha, stats, counts);
  k_scan<<<1, 1, 0, stream>>>(counts, basep, cur);
  k_ln_scatter<<<NT, 256, 0, stream>>>(x, ln_g, ln_b, eid, stats, cur, rowtok, xln);
  k_transpose<<<dim3(FDIM / 128, DIM / 64, NEXP), 256, 0, stream>>>(w1, w1t, DIM, FDIM);
  k_transpose<<<dim3(DIM / 128, FDIM / 64, NEXP), 256, 0, stream>>>(w2, w2t, FDIM, DIM);
  k_gemm<DIM, FDIM, true><<<NEXP * (NT / 128) * (FDIM / 128), 256, 0, stream>>>(
      xln, w1t, b1, basep, counts, hbuf, nullptr, nullptr, nullptr, nullptr);
  k_gemm<FDIM, DIM, false><<<NEXP * (NT / 128) * (DIM / 128), 256, 0, stream>>>(
      hbuf, w2t, b2, basep, counts, nullptr, rowtok, alpha, x, out);
}

// Round 11
// 441.985 us; speedup vs baseline: 1.7215x; 1.2074x over previous
//
#include <hip/hip_runtime.h>

#define NT 8192      // tokens = B*S
#define DIM 1024     // D
#define FDIM 4096    // F
#define NEXP 8       // experts

typedef __attribute__((ext_vector_type(8))) short bfx8;   // 8 bf16 (4 VGPRs)
typedef __attribute__((ext_vector_type(4))) float fx4;    // MFMA accumulator

__device__ __forceinline__ unsigned short f2bf(float f) {
  union { float f; unsigned u; } v; v.f = f;
  unsigned u = v.u;
  unsigned r = u + 0x7FFFu + ((u >> 16) & 1u);   // round-to-nearest-even
  return (unsigned short)(r >> 16);
}

__device__ __forceinline__ void gload16(const void* g, void* l) {
  __builtin_amdgcn_global_load_lds(
      (const __attribute__((address_space(1))) unsigned int*)g,
      (__attribute__((address_space(3))) unsigned int*)l, 16, 0, 0);
}

// ---------------- zero counters ----------------
__global__ void k_zero(int* __restrict__ counts) {
  if (threadIdx.x < NEXP) counts[threadIdx.x] = 0;
}

// ---------------- 64x128 transpose tile: fp32 [R][C] -> bf16 [C][R] ----------------
// v4 (proven R8-R10): gload_lds staging, XOR-swizzled source cols, swizzled read.
__device__ __forceinline__ void tr_tile(
    const float* __restrict__ src, unsigned short* __restrict__ dst,
    int R, int C, int r0, int c0, float* T, int t)
{
  const int lane = t & 63, wv = t >> 6;
  const int rsub = wv * 2 + (lane >> 5);           // == row&7 for all i
  const int cb = (lane & 31) ^ rsub;               // swizzled source col-block
#pragma unroll
  for (int i = 0; i < 8; ++i) {
    const int rbase = i * 8 + wv * 2;              // wave-uniform row pair
    gload16(src + (size_t)(r0 + rbase + (lane >> 5)) * C + c0 + cb * 4,
            &T[rbase * 128]);
  }
  __syncthreads();
#pragma unroll
  for (int it = 0; it < 4; ++it) {
    const int c = (t >> 3) + it * 32, q = t & 7;
    unsigned short o[8];
#pragma unroll
    for (int u = 0; u < 8; ++u)
      o[u] = f2bf(T[(q * 8 + u) * 128 + ((((c >> 2) ^ u) << 2) | (c & 3))]);
    *(uint4*)(dst + (size_t)(c0 + c) * R + r0 + q * 8) = *(const uint4*)o;
  }
}

// ---------------- mega pre-pass: routing+LN-apply | w1 transpose | w2 transpose ----
// blocks [0,NT): routing + in-kernel LN -> xln (NATURAL token order);
// [NT, NT+4096): w1t tiles; [NT+4096, NT+8192): w2t tiles.
__global__ __launch_bounds__(256) void k_fused(
    const float* __restrict__ x, const float* __restrict__ cent,
    const float* __restrict__ g, const float* __restrict__ b,
    const float* __restrict__ w1, const float* __restrict__ w2,
    int* __restrict__ eid, float* __restrict__ alpha, int* __restrict__ counts,
    unsigned short* __restrict__ xln,
    unsigned short* __restrict__ w1t, unsigned short* __restrict__ w2t)
{
  __shared__ float T[64 * 128];
  __shared__ float part[4][NEXP], ps[4], pss[4];
  __shared__ float sMu, sRstd;
  __shared__ int sE;
  const int bid = blockIdx.x, tid = threadIdx.x;

  if (bid < NT) {
    const int t = bid;
    const float4 xv = ((const float4*)(x + (size_t)t * DIM))[tid];
    float acc[NEXP];
#pragma unroll
    for (int e = 0; e < NEXP; ++e) {
      const float4 cv = ((const float4*)(cent + (size_t)e * DIM))[tid];
      acc[e] = xv.x * cv.x + xv.y * cv.y + xv.z * cv.z + xv.w * cv.w;
    }
    float s = xv.x + xv.y + xv.z + xv.w;
    float ss = xv.x * xv.x + xv.y * xv.y + xv.z * xv.z + xv.w * xv.w;
#pragma unroll
    for (int off = 32; off > 0; off >>= 1) {
#pragma unroll
      for (int e = 0; e < NEXP; ++e) acc[e] += __shfl_down(acc[e], off);
      s += __shfl_down(s, off); ss += __shfl_down(ss, off);
    }
    const int lane = tid & 63, w = tid >> 6;
    if (lane == 0) {
#pragma unroll
      for (int e = 0; e < NEXP; ++e) part[w][e] = acc[e];
      ps[w] = s; pss[w] = ss;
    }
    __syncthreads();
    if (tid == 0) {
      int best = 0; float bv = -1e30f;
#pragma unroll
      for (int e = 0; e < NEXP; ++e) {
        float v = part[0][e] + part[1][e] + part[2][e] + part[3][e];
        if (v > bv) { bv = v; best = e; }   // strict >: first max (matches argmax)
      }
      eid[t] = best;
      alpha[t] = 1.0f / (1.0f + expf(-bv));
      atomicAdd(&counts[best], 1);
      const float sum = ps[0] + ps[1] + ps[2] + ps[3];
      const float sq  = pss[0] + pss[1] + pss[2] + pss[3];
      const float mu = sum * (1.0f / DIM);
      const float var = sq * (1.0f / DIM) - mu * mu;
      sE = best; sMu = mu; sRstd = rsqrtf(var + 1e-5f);
    }
    __syncthreads();
    const int e = sE;
    const float mu = sMu, rstd = sRstd;
    const float4 gv = ((const float4*)(g + (size_t)e * DIM))[tid];
    const float4 bv4 = ((const float4*)(b + (size_t)e * DIM))[tid];
    ushort4 o;
    o.x = f2bf((xv.x - mu) * rstd * gv.x + bv4.x);
    o.y = f2bf((xv.y - mu) * rstd * gv.y + bv4.y);
    o.z = f2bf((xv.z - mu) * rstd * gv.z + bv4.z);
    o.w = f2bf((xv.w - mu) * rstd * gv.w + bv4.w);
    ((ushort4*)(xln + (size_t)t * DIM))[tid] = o;
  } else if (bid < NT + 4096) {
    // w1 [E][D][F] -> w1t [E][F][D]: R=1024, C=4096; 16 r-tiles x 32 c-tiles
    const int i = bid - NT;
    const int e = i >> 9, rem = i & 511;
    tr_tile(w1 + (size_t)e * DIM * FDIM, w1t + (size_t)e * DIM * FDIM,
            DIM, FDIM, (rem & 15) * 64, (rem >> 4) * 128, T, tid);
  } else {
    // w2 [E][F][D] -> w2t [E][D][F]: R=4096, C=1024; 64 r-tiles x 8 c-tiles
    const int i = bid - NT - 4096;
    const int e = i >> 9, rem = i & 511;
    tr_tile(w2 + (size_t)e * FDIM * DIM, w2t + (size_t)e * FDIM * DIM,
            FDIM, DIM, (rem >> 3) * 64, (rem & 7) * 128, T, tid);
  }
}

// ---------------- exclusive scan of 8 counts ----------------
__global__ void k_scan(const int* __restrict__ counts, int* __restrict__ bs, int* __restrict__ cur) {
  if (threadIdx.x == 0) {
    int s = 0;
    for (int e = 0; e < NEXP; ++e) { bs[e] = s; cur[e] = s; s += counts[e]; }
  }
}

// ---------------- build pos -> token map (index-only counting sort) ----------------
__global__ void k_rowtok(const int* __restrict__ eid, int* __restrict__ cur,
                         int* __restrict__ row_tok) {
  const int t = blockIdx.x * 256 + threadIdx.x;
  const int e = eid[t];
  const int pos = atomicAdd(&cur[e], 1);
  row_tok[pos] = t;
}

// ---------------- grouped MFMA GEMM, 128x128 tile, BK=32, 4 waves ----------------
// R10-proven kernel; FIRST gathers A rows via row_tok (per-lane gload source).
// Grid 1D: expert = bid&7 (== XCD), n-panel, m fastest (weights L2-resident).
template<int K, int N, bool FIRST>
__global__ __launch_bounds__(256) void k_gemm(
    const unsigned short* __restrict__ A,
    const unsigned short* __restrict__ Bt,
    const float* __restrict__ bias,
    const int* __restrict__ bs, const int* __restrict__ counts,
    unsigned short* __restrict__ Hout,
    const int* __restrict__ row_tok, const float* __restrict__ alpha,
    const float* __restrict__ xin, float* __restrict__ out)
{
  const int MB = NT / 128;
  const int bid = blockIdx.x;
  const int e = bid & 7;
  const int l = bid >> 3;
  const int m0 = (l % MB) * 128;               // m fastest
  const int cnt = counts[e];
  if (m0 >= cnt) return;
  const int n0 = (l / MB) * 128;
  const int rbase = bs[e];

  // 16.9KB shared: K-loop uses [0,16KB) as lA/lB; epilogue reuses as 32x132 fp32
  __shared__ __align__(16) char smem[32 * 132 * 4];
  unsigned short* lA = (unsigned short*)smem;
  unsigned short* lB = (unsigned short*)(smem + 8192);
  float* Lf = (float*)smem;

  const int tid = threadIdx.x;
  const int lane = tid & 63, wv = tid >> 6;
  const int wm = (wv >> 1) * 64, wn = (wv & 1) * 64;
  const int lr = lane & 15, lg = lane >> 4;

  fx4 acc[4][4] = {};

  const unsigned short* Bte = Bt + (size_t)e * N * K;

  // staging: chunk g = p*256+tid -> row g>>2, k-off (g&3)*8;
  // LDS linear elem offset 8*g = wave-uniform (p*4+wv)*512 + lane*8.
  const unsigned short* aP[2];
  const unsigned short* bP[2];
#pragma unroll
  for (int p = 0; p < 2; ++p) {
    const int g = p * 256 + tid;
    const int row = g >> 2, kq = (g & 3) * 8;
    int ar = rbase + m0 + row;
    ar = ar < NT ? ar : NT - 1;               // clamp: pad rows masked at epilogue
    if constexpr (FIRST) {
      const int tok = row_tok[ar];            // gather: xln is natural order
      aP[p] = A + (size_t)tok * K + kq;
    } else {
      aP[p] = A + (size_t)ar * K + kq;        // hbuf is sorted order
    }
    bP[p] = Bte + (size_t)(n0 + row) * K + kq;
  }

  for (int k0 = 0; k0 < K; k0 += 32) {
    gload16(aP[0] + k0, &lA[(0 * 4 + wv) * 512]);
    gload16(aP[1] + k0, &lA[(1 * 4 + wv) * 512]);
    gload16(bP[0] + k0, &lB[(0 * 4 + wv) * 512]);
    gload16(bP[1] + k0, &lB[(1 * 4 + wv) * 512]);
    __syncthreads();                          // compiler-managed vmcnt drain
    bfx8 bf[4];
#pragma unroll
    for (int j = 0; j < 4; ++j)
      bf[j] = *(const bfx8*)(&lB[(wn + j * 16 + lr) * 32 + lg * 8]);
#pragma unroll
    for (int i = 0; i < 4; ++i) {
      const bfx8 af = *(const bfx8*)(&lA[(wm + i * 16 + lr) * 32 + lg * 8]);
#pragma unroll
      for (int j = 0; j < 4; ++j)
        acc[i][j] = __builtin_amdgcn_mfma_f32_16x16x32_bf16(af, bf[j], acc[i][j], 0, 0, 0);
    }
    __syncthreads();
  }

  // bias for this thread's 4 columns
  const float* be = bias + (size_t)e * N;
  float bcol[4];
#pragma unroll
  for (int j = 0; j < 4; ++j) bcol[j] = be[n0 + wn + j * 16 + lr];

#pragma unroll
  for (int i = 0; i < 4; ++i) {
    __syncthreads();                          // protect LDS reuse
#pragma unroll
    for (int r2 = 0; r2 < 4; ++r2) {
      const int rowp = (wv >> 1) * 16 + lg * 4 + r2;    // 0..31
#pragma unroll
      for (int j = 0; j < 4; ++j) {
        float v = acc[i][j][r2] + bcol[j];
        if (FIRST) v = v > 0.f ? v : 0.f;
        Lf[rowp * 132 + wn + j * 16 + lr] = v;
      }
    }
    __syncthreads();
    if constexpr (FIRST) {
#pragma unroll
      for (int s = 0; s < 2; ++s) {
        const int tsk = tid + 256 * s;                  // 0..511
        const int rr = tsk >> 4, cg = tsk & 15;
        const int ra = i * 16 + ((rr >> 4) << 6) + (rr & 15);
        if (m0 + ra < cnt) {
          const float4 a = *(const float4*)&Lf[rr * 132 + cg * 8];
          const float4 b = *(const float4*)&Lf[rr * 132 + cg * 8 + 4];
          unsigned short o[8] = { f2bf(a.x), f2bf(a.y), f2bf(a.z), f2bf(a.w),
                                  f2bf(b.x), f2bf(b.y), f2bf(b.z), f2bf(b.w) };
          *(uint4*)(Hout + (size_t)(rbase + m0 + ra) * N + n0 + cg * 8) =
              *(const uint4*)o;
        }
      }
    } else {
#pragma unroll
      for (int s = 0; s < 4; ++s) {
        const int tsk = tid + 256 * s;                  // 0..1023
        const int rr = tsk >> 5, c4 = tsk & 31;
        const int ra = i * 16 + ((rr >> 4) << 6) + (rr & 15);
        if (m0 + ra < cnt) {
          const int tok = row_tok[rbase + m0 + ra];
          const float al = alpha[tok];
          const float4 v = *(const float4*)&Lf[rr * 132 + c4 * 4];
          const float4 xr = *(const float4*)(xin + (size_t)tok * N + n0 + c4 * 4);
          float4 o;
          o.x = xr.x + al * v.x;
          o.y = xr.y + al * v.y;
          o.z = xr.z + al * v.z;
          o.w = xr.w + al * v.w;
          *(float4*)(out + (size_t)tok * N + n0 + c4 * 4) = o;
        }
      }
    }
  }
}

extern "C" void kernel_launch(void* const* d_in, const int* in_sizes, int n_in,
                              void* d_out, int out_size, void* d_ws, size_t ws_size,
                              hipStream_t stream)
{
  const float* x    = (const float*)d_in[0];
  const float* cent = (const float*)d_in[1];
  const float* ln_g = (const float*)d_in[2];
  const float* ln_b = (const float*)d_in[3];
  const float* w1   = (const float*)d_in[4];
  const float* b1   = (const float*)d_in[5];
  const float* w2   = (const float*)d_in[6];
  const float* b2   = (const float*)d_in[7];
  float* out = (float*)d_out;

  char* ws = (char*)d_ws;
  unsigned short* xln  = (unsigned short*)(ws);                          // 16 MB [NT][DIM] bf16 (natural order)
  unsigned short* hbuf = (unsigned short*)(ws + (16ull << 20));          // 64 MB [NT][FDIM] bf16 (sorted order)
  unsigned short* w1t  = (unsigned short*)(ws + (80ull << 20));          // 64 MB [E][F][D] bf16
  unsigned short* w2t  = (unsigned short*)(ws + (144ull << 20));         // 64 MB [E][D][F] bf16
  char* tail = ws + (208ull << 20);
  int*    eid    = (int*)(tail);
  float*  alpha  = (float*)(tail + 32768);
  int*    rowtok = (int*)(tail + 65536);
  int*    counts = (int*)(tail + 98304);
  int*    basep  = counts + 16;
  int*    cur    = counts + 32;

  k_zero<<<1, 64, 0, stream>>>(counts);
  k_fused<<<NT + 8192, 256, 0, stream>>>(
      x, cent, ln_g, ln_b, w1, w2, eid, alpha, counts, xln, w1t, w2t);
  k_scan<<<1, 1, 0, stream>>>(counts, basep, cur);
  k_rowtok<<<NT / 256, 256, 0, stream>>>(eid, cur, rowtok);
  k_gemm<DIM, FDIM, true><<<NEXP * (NT / 128) * (FDIM / 128), 256, 0, stream>>>(
      xln, w1t, b1, basep, counts, hbuf, rowtok, nullptr, nullptr, nullptr);
  k_gemm<FDIM, DIM, false><<<NEXP * (NT / 128) * (DIM / 128), 256, 0, stream>>>(
      hbuf, w2t, b2, basep, counts, nullptr, rowtok, alpha, x, out);
}